// Round 4
// baseline (616.527 us; speedup 1.0000x reference)
//
#include <hip/hip_runtime.h>
#include <hip/hip_bf16.h>

typedef __bf16 bf16_t;
typedef __attribute__((ext_vector_type(8))) __bf16 bf16x8;
typedef __attribute__((ext_vector_type(4))) float f32x4;

#define MFMA16(a, b, c) __builtin_amdgcn_mfma_f32_16x16x32_bf16((a), (b), (c), 0, 0, 0)

__device__ __forceinline__ unsigned short f2bf(float f) {
    bf16_t b = (bf16_t)f;
    return __builtin_bit_cast(unsigned short, b);
}

// Stage a 128(rows) x 64(k) bf16 tile from bf16 global (row-major, ld elems)
// into LDS [128][64] row-major. VGPR round-trip, conflict-free tid*16B writes.
__device__ __forceinline__ void stage_tile_bf(const bf16_t* __restrict__ g, int ld,
                                              bf16_t* lds, int tid) {
#pragma unroll
    for (int p = 0; p < 4; ++p) {
        int row = p * 32 + (tid >> 3);   // 8 lanes cover one row's 64 k-elems
        int c = tid & 7;                 // 16B chunk within the row
        bf16x8 v = *(const bf16x8*)(g + (size_t)row * ld + c * 8);
        *(bf16x8*)(lds + p * 2048 + tid * 8) = v;
    }
}

// Same, but global source is fp32: load 8 floats (2x float4), convert to bf16.
__device__ __forceinline__ void stage_tile_f32(const float* __restrict__ g, int ld,
                                               bf16_t* lds, int tid) {
#pragma unroll
    for (int p = 0; p < 4; ++p) {
        int row = p * 32 + (tid >> 3);
        int c = tid & 7;
        const float* src = g + (size_t)row * ld + c * 8;
        f32x4 v0 = *(const f32x4*)(src);
        f32x4 v1 = *(const f32x4*)(src + 4);
        bf16x8 o;
        o[0] = (bf16_t)v0[0]; o[1] = (bf16_t)v0[1];
        o[2] = (bf16_t)v0[2]; o[3] = (bf16_t)v0[3];
        o[4] = (bf16_t)v1[0]; o[5] = (bf16_t)v1[1];
        o[6] = (bf16_t)v1[2]; o[7] = (bf16_t)v1[3];
        *(bf16x8*)(lds + p * 2048 + tid * 8) = o;
    }
}

// Read one 8-bf16 fragment (row r, k-chunk 'chunk') from a [128][64] tile.
__device__ __forceinline__ bf16x8 read_frag(const bf16_t* lds, int r, int chunk) {
    return *(const bf16x8*)(lds + r * 64 + chunk * 8);
}

// ---------- batched 64x64 transpose + fp32->bf16 convert ----------
// src: fp32 [batch][R][C] -> dst: bf16 [batch][C][R]
__global__ __launch_bounds__(256) void transcvt64(const float* __restrict__ src,
                                                  unsigned short* __restrict__ dst,
                                                  int R, int C) {
    __shared__ __align__(16) unsigned short tile[64][66];  // +2 pad
    size_t off = (size_t)blockIdx.z * R * C;
    const float* s = src + off;
    unsigned short* d = dst + off;
    int tr = blockIdx.y * 64, tc = blockIdx.x * 64;
    int tid = threadIdx.x;
    int lr = tid >> 4;          // 0..15
    int lc = (tid & 15) * 4;    // 0..60 step 4
#pragma unroll
    for (int p = 0; p < 4; ++p) {
        int r = p * 16 + lr;
        f32x4 v = *(const f32x4*)(s + (size_t)(tr + r) * C + tc + lc);
        tile[r][lc + 0] = f2bf(v[0]); tile[r][lc + 1] = f2bf(v[1]);
        tile[r][lc + 2] = f2bf(v[2]); tile[r][lc + 3] = f2bf(v[3]);
    }
    __syncthreads();
#pragma unroll
    for (int p = 0; p < 4; ++p) {
        int oc = p * 16 + lr;   // source column
        ushort4 v;
        v.x = tile[lc + 0][oc]; v.y = tile[lc + 1][oc];
        v.z = tile[lc + 2][oc]; v.w = tile[lc + 3][oc];
        *(ushort4*)(d + (size_t)(tc + oc) * R + tr + lc) = v;
    }
}

// ---------- GEMM1: U = X*W1, V = X*W3, Hh = silu(U)*V ----------
// Xc: fp32 chunk [R,1024] k-contig. W1t/W3t: bf16 [4][2048][1024] (n-major,
// k-contig). Hh: bf16 [R,2048]. Grid: (16 col-tiles, R/128 row-tiles).
__global__ __launch_bounds__(256) void gemm13(const float* __restrict__ Xc,
                                              const bf16_t* __restrict__ W1t,
                                              const bf16_t* __restrict__ W3t,
                                              bf16_t* __restrict__ Hh,
                                              int row_base) {
    const int K = 1024, N = 2048;
    int col0 = blockIdx.x * 128;
    int row0 = blockIdx.y * 128;
    int seg = ((row_base + row0) & 2047) >> 9;   // abs_row % 2048 / 512
    const float*  A  = Xc + (size_t)row0 * K;
    const bf16_t* B1 = W1t + (size_t)seg * N * K + (size_t)col0 * K;
    const bf16_t* B3 = W3t + (size_t)seg * N * K + (size_t)col0 * K;

    __shared__ __align__(16) bf16_t sA[128 * 64];
    __shared__ __align__(16) bf16_t sB1[128 * 64];
    __shared__ __align__(16) bf16_t sB3[128 * 64];

    int tid = threadIdx.x;
    int lane = tid & 63, wave = tid >> 6;
    int wm = wave & 1, wn = wave >> 1;
    int quad = lane >> 4, l16 = lane & 15;

    f32x4 accU[4][4], accV[4][4];
    f32x4 z = {0.f, 0.f, 0.f, 0.f};
#pragma unroll
    for (int i = 0; i < 4; ++i)
#pragma unroll
        for (int j = 0; j < 4; ++j) { accU[i][j] = z; accV[i][j] = z; }

    for (int kt = 0; kt < K / 64; ++kt) {
        __syncthreads();
        stage_tile_f32(A + kt * 64, K, sA, tid);
        stage_tile_bf(B1 + kt * 64, K, sB1, tid);
        stage_tile_bf(B3 + kt * 64, K, sB3, tid);
        __syncthreads();
#pragma unroll
        for (int kk = 0; kk < 2; ++kk) {
            int chunk = kk * 4 + quad;   // operand layout: k = chunk*8 + j
            bf16x8 af[4], b1f[4], b3f[4];
#pragma unroll
            for (int i = 0; i < 4; ++i) af[i] = read_frag(sA, wm * 64 + i * 16 + l16, chunk);
#pragma unroll
            for (int j = 0; j < 4; ++j) b1f[j] = read_frag(sB1, wn * 64 + j * 16 + l16, chunk);
#pragma unroll
            for (int j = 0; j < 4; ++j) b3f[j] = read_frag(sB3, wn * 64 + j * 16 + l16, chunk);
#pragma unroll
            for (int i = 0; i < 4; ++i)
#pragma unroll
                for (int j = 0; j < 4; ++j) {
                    accU[i][j] = MFMA16(af[i], b1f[j], accU[i][j]);
                    accV[i][j] = MFMA16(af[i], b3f[j], accV[i][j]);
                }
        }
    }

    // Epilogue: Hh = silu(U) * V.  C/D layout: col = lane&15, row = quad*4+reg.
#pragma unroll
    for (int i = 0; i < 4; ++i)
#pragma unroll
        for (int j = 0; j < 4; ++j) {
            int r = row0 + wm * 64 + i * 16 + quad * 4;
            int c = col0 + wn * 64 + j * 16 + l16;
#pragma unroll
            for (int t = 0; t < 4; ++t) {
                float u = accU[i][j][t];
                float v = accV[i][j][t];
                float h = (u / (1.f + __expf(-u))) * v;
                Hh[(size_t)(r + t) * N + c] = (bf16_t)h;
            }
        }
}

// ---------- GEMM2: Out = Hh * W2 ----------
// Hh: bf16 chunk [R,2048] k-contig. W2t: bf16 [4][1024][2048] (n-major,
// k-contig). Outc: fp32 chunk [R,1024]. Grid: (8 col-tiles, R/128 row-tiles).
__global__ __launch_bounds__(256) void gemm2k(const bf16_t* __restrict__ Hh,
                                              const bf16_t* __restrict__ W2t,
                                              float* __restrict__ Outc,
                                              int row_base) {
    const int K = 2048, N = 1024;
    int col0 = blockIdx.x * 128;
    int row0 = blockIdx.y * 128;
    int seg = ((row_base + row0) & 2047) >> 9;
    const bf16_t* A = Hh + (size_t)row0 * K;
    const bf16_t* B = W2t + (size_t)seg * N * K + (size_t)col0 * K;

    __shared__ __align__(16) bf16_t sA[128 * 64];
    __shared__ __align__(16) bf16_t sB[128 * 64];

    int tid = threadIdx.x;
    int lane = tid & 63, wave = tid >> 6;
    int wm = wave & 1, wn = wave >> 1;
    int quad = lane >> 4, l16 = lane & 15;

    f32x4 acc[4][4];
    f32x4 z = {0.f, 0.f, 0.f, 0.f};
#pragma unroll
    for (int i = 0; i < 4; ++i)
#pragma unroll
        for (int j = 0; j < 4; ++j) acc[i][j] = z;

    for (int kt = 0; kt < K / 64; ++kt) {
        __syncthreads();
        stage_tile_bf(A + kt * 64, K, sA, tid);
        stage_tile_bf(B + kt * 64, K, sB, tid);
        __syncthreads();
#pragma unroll
        for (int kk = 0; kk < 2; ++kk) {
            int chunk = kk * 4 + quad;
            bf16x8 af[4], bf[4];
#pragma unroll
            for (int i = 0; i < 4; ++i) af[i] = read_frag(sA, wm * 64 + i * 16 + l16, chunk);
#pragma unroll
            for (int j = 0; j < 4; ++j) bf[j] = read_frag(sB, wn * 64 + j * 16 + l16, chunk);
#pragma unroll
            for (int i = 0; i < 4; ++i)
#pragma unroll
                for (int j = 0; j < 4; ++j)
                    acc[i][j] = MFMA16(af[i], bf[j], acc[i][j]);
        }
    }

#pragma unroll
    for (int i = 0; i < 4; ++i)
#pragma unroll
        for (int j = 0; j < 4; ++j) {
            int r = row0 + wm * 64 + i * 16 + quad * 4;
            int c = col0 + wn * 64 + j * 16 + l16;
#pragma unroll
            for (int t = 0; t < 4; ++t)
                Outc[(size_t)(r + t) * N + c] = acc[i][j][t];
        }
}

extern "C" void kernel_launch(void* const* d_in, const int* in_sizes, int n_in,
                              void* d_out, int out_size, void* d_ws, size_t ws_size,
                              hipStream_t stream) {
    const float* x  = (const float*)d_in[0];   // fp32 [8,2048,1024]
    const float* w1 = (const float*)d_in[1];   // fp32 [4,1024,2048]
    const float* w3 = (const float*)d_in[2];   // fp32 [4,1024,2048]
    const float* w2 = (const float*)d_in[3];   // fp32 [4,2048,1024]
    float* out = (float*)d_out;                // fp32 [8,2048,1024]

    const size_t WSEG = (size_t)4 * 1024 * 2048; // elems per weight tensor
    bf16_t* w1t = (bf16_t*)d_ws;                 // bf16 [4][2048][1024] (16.8 MB)
    bf16_t* w3t = w1t + WSEG;                    // bf16 [4][2048][1024]
    bf16_t* w2t = w3t + WSEG;                    // bf16 [4][1024][2048]
    bf16_t* Hh  = w2t + WSEG;                    // bf16 chunk [R,2048]

    transcvt64<<<dim3(32, 16, 4), 256, 0, stream>>>(w1, (unsigned short*)w1t, 1024, 2048);
    transcvt64<<<dim3(32, 16, 4), 256, 0, stream>>>(w3, (unsigned short*)w3t, 1024, 2048);
    transcvt64<<<dim3(16, 32, 4), 256, 0, stream>>>(w2, (unsigned short*)w2t, 2048, 1024);

    // Adaptive Hh chunking vs ws_size (host constant -> capture-safe).
    const int TOTAL_ROWS = 16384;
    size_t wbytes = 3 * WSEG * sizeof(bf16_t);   // 50.3 MB for weights
    size_t avail = (ws_size > wbytes) ? ws_size - wbytes : 0;
    int chunk_rows = TOTAL_ROWS;
    while (chunk_rows > 128 && (size_t)chunk_rows * 2048 * sizeof(bf16_t) > avail)
        chunk_rows >>= 1;

    for (int rb = 0; rb < TOTAL_ROWS; rb += chunk_rows) {
        gemm13<<<dim3(16, chunk_rows / 128), 256, 0, stream>>>(
            x + (size_t)rb * 1024, w1t, w3t, Hh, rb);
        gemm2k<<<dim3(8, chunk_rows / 128), 256, 0, stream>>>(
            Hh, w2t, out + (size_t)rb * 1024, rb);
    }
}

// Round 5
// 575.093 us; speedup vs baseline: 1.0720x; 1.0720x over previous
//
#include <hip/hip_runtime.h>
#include <hip/hip_bf16.h>

typedef __bf16 bf16_t;
typedef __attribute__((ext_vector_type(8))) __bf16 bf16x8;
typedef __attribute__((ext_vector_type(4))) float f32x4;

#define MFMA16(a, b, c) __builtin_amdgcn_mfma_f32_16x16x32_bf16((a), (b), (c), 0, 0, 0)

__device__ __forceinline__ unsigned short f2bf(float f) {
    bf16_t b = (bf16_t)f;
    return __builtin_bit_cast(unsigned short, b);
}

__device__ __forceinline__ void gload16(const void* g, void* l) {
    __builtin_amdgcn_global_load_lds(
        (const __attribute__((address_space(1))) void*)g,
        (__attribute__((address_space(3))) void*)l,
        16, 0, 0);
}

// Stage a 128(rows) x 64(k) bf16 tile from global (row-major, ld elems) into
// LDS [128][64] row-major via global_load_lds (async, no VGPR round-trip).
// LDS dest byte-offset = p*4096 + wave*1024 + lane*16: wave-uniform base +
// lane*16 as the HW requires (m104/m108). Global side: 8 lanes cover one
// row's 128 B, lane-contiguous.
__device__ __forceinline__ void stage_tile(const bf16_t* __restrict__ g, int ld,
                                           bf16_t* lds, int tid) {
#pragma unroll
    for (int p = 0; p < 4; ++p) {
        int row = p * 32 + (tid >> 3);
        int c = tid & 7;
        gload16(g + (size_t)row * ld + c * 8, lds + p * 2048 + tid * 8);
    }
}

// Read one 8-bf16 fragment (row r, k-chunk 'chunk') from a [128][64] tile.
__device__ __forceinline__ bf16x8 read_frag(const bf16_t* lds, int r, int chunk) {
    return *(const bf16x8*)(lds + r * 64 + chunk * 8);
}

// ---------- fp32 -> bf16 elementwise convert (for X) ----------
// n must be a multiple of 2048; grid = n/2048, 256 threads, 8 elems/thread.
__global__ __launch_bounds__(256) void cvtx(const float* __restrict__ src,
                                            bf16_t* __restrict__ dst) {
    size_t i = ((size_t)blockIdx.x * 256 + threadIdx.x) * 8;
    f32x4 v0 = *(const f32x4*)(src + i);
    f32x4 v1 = *(const f32x4*)(src + i + 4);
    bf16x8 o;
    o[0] = (bf16_t)v0[0]; o[1] = (bf16_t)v0[1];
    o[2] = (bf16_t)v0[2]; o[3] = (bf16_t)v0[3];
    o[4] = (bf16_t)v1[0]; o[5] = (bf16_t)v1[1];
    o[6] = (bf16_t)v1[2]; o[7] = (bf16_t)v1[3];
    *(bf16x8*)(dst + i) = o;
}

// ---------- batched 64x64 transpose + fp32->bf16 convert ----------
// src: fp32 [batch][R][C] -> dst: bf16 [batch][C][R]
__global__ __launch_bounds__(256) void transcvt64(const float* __restrict__ src,
                                                  unsigned short* __restrict__ dst,
                                                  int R, int C) {
    __shared__ __align__(16) unsigned short tile[64][66];  // +2 pad
    size_t off = (size_t)blockIdx.z * R * C;
    const float* s = src + off;
    unsigned short* d = dst + off;
    int tr = blockIdx.y * 64, tc = blockIdx.x * 64;
    int tid = threadIdx.x;
    int lr = tid >> 4;          // 0..15
    int lc = (tid & 15) * 4;    // 0..60 step 4
#pragma unroll
    for (int p = 0; p < 4; ++p) {
        int r = p * 16 + lr;
        f32x4 v = *(const f32x4*)(s + (size_t)(tr + r) * C + tc + lc);
        tile[r][lc + 0] = f2bf(v[0]); tile[r][lc + 1] = f2bf(v[1]);
        tile[r][lc + 2] = f2bf(v[2]); tile[r][lc + 3] = f2bf(v[3]);
    }
    __syncthreads();
#pragma unroll
    for (int p = 0; p < 4; ++p) {
        int oc = p * 16 + lr;   // source column
        ushort4 v;
        v.x = tile[lc + 0][oc]; v.y = tile[lc + 1][oc];
        v.z = tile[lc + 2][oc]; v.w = tile[lc + 3][oc];
        *(ushort4*)(d + (size_t)(tc + oc) * R + tr + lc) = v;
    }
}

// ---------- GEMM1: U = X*W1, V = X*W3, Hh = silu(U)*V ----------
// Xb: bf16 chunk [R,1024] k-contig. W1t/W3t: bf16 [4][2048][1024] (n-major,
// k-contig). Hh: bf16 [R,2048]. Grid: (16 col-tiles, R/128 row-tiles).
__global__ __launch_bounds__(256) void gemm13(const bf16_t* __restrict__ Xb,
                                              const bf16_t* __restrict__ W1t,
                                              const bf16_t* __restrict__ W3t,
                                              bf16_t* __restrict__ Hh,
                                              int row_base) {
    const int K = 1024, N = 2048;
    int col0 = blockIdx.x * 128;
    int row0 = blockIdx.y * 128;
    int seg = ((row_base + row0) & 2047) >> 9;   // abs_row % 2048 / 512
    const bf16_t* A  = Xb + (size_t)row0 * K;
    const bf16_t* B1 = W1t + (size_t)seg * N * K + (size_t)col0 * K;
    const bf16_t* B3 = W3t + (size_t)seg * N * K + (size_t)col0 * K;

    __shared__ __align__(16) bf16_t sA[128 * 64];
    __shared__ __align__(16) bf16_t sB1[128 * 64];
    __shared__ __align__(16) bf16_t sB3[128 * 64];

    int tid = threadIdx.x;
    int lane = tid & 63, wave = tid >> 6;
    int wm = wave & 1, wn = wave >> 1;
    int quad = lane >> 4, l16 = lane & 15;

    f32x4 accU[4][4], accV[4][4];
    f32x4 z = {0.f, 0.f, 0.f, 0.f};
#pragma unroll
    for (int i = 0; i < 4; ++i)
#pragma unroll
        for (int j = 0; j < 4; ++j) { accU[i][j] = z; accV[i][j] = z; }

    for (int kt = 0; kt < K / 64; ++kt) {
        __syncthreads();
        stage_tile(A + kt * 64, K, sA, tid);
        stage_tile(B1 + kt * 64, K, sB1, tid);
        stage_tile(B3 + kt * 64, K, sB3, tid);
        __syncthreads();
#pragma unroll
        for (int kk = 0; kk < 2; ++kk) {
            int chunk = kk * 4 + quad;   // operand layout: k = chunk*8 + j
            bf16x8 af[4], b1f[4], b3f[4];
#pragma unroll
            for (int i = 0; i < 4; ++i) af[i] = read_frag(sA, wm * 64 + i * 16 + l16, chunk);
#pragma unroll
            for (int j = 0; j < 4; ++j) b1f[j] = read_frag(sB1, wn * 64 + j * 16 + l16, chunk);
#pragma unroll
            for (int j = 0; j < 4; ++j) b3f[j] = read_frag(sB3, wn * 64 + j * 16 + l16, chunk);
#pragma unroll
            for (int i = 0; i < 4; ++i)
#pragma unroll
                for (int j = 0; j < 4; ++j) {
                    accU[i][j] = MFMA16(af[i], b1f[j], accU[i][j]);
                    accV[i][j] = MFMA16(af[i], b3f[j], accV[i][j]);
                }
        }
    }

    // Epilogue: Hh = silu(U) * V.  C/D layout: col = lane&15, row = quad*4+reg.
#pragma unroll
    for (int i = 0; i < 4; ++i)
#pragma unroll
        for (int j = 0; j < 4; ++j) {
            int r = row0 + wm * 64 + i * 16 + quad * 4;
            int c = col0 + wn * 64 + j * 16 + l16;
#pragma unroll
            for (int t = 0; t < 4; ++t) {
                float u = accU[i][j][t];
                float v = accV[i][j][t];
                float h = (u / (1.f + __expf(-u))) * v;
                Hh[(size_t)(r + t) * N + c] = (bf16_t)h;
            }
        }
}

// ---------- GEMM2: Out = Hh * W2 ----------
// Hh: bf16 chunk [R,2048] k-contig. W2t: bf16 [4][1024][2048] (n-major,
// k-contig). Outc: fp32 chunk [R,1024]. Grid: (8 col-tiles, R/128 row-tiles).
__global__ __launch_bounds__(256) void gemm2k(const bf16_t* __restrict__ Hh,
                                              const bf16_t* __restrict__ W2t,
                                              float* __restrict__ Outc,
                                              int row_base) {
    const int K = 2048, N = 1024;
    int col0 = blockIdx.x * 128;
    int row0 = blockIdx.y * 128;
    int seg = ((row_base + row0) & 2047) >> 9;
    const bf16_t* A = Hh + (size_t)row0 * K;
    const bf16_t* B = W2t + (size_t)seg * N * K + (size_t)col0 * K;

    __shared__ __align__(16) bf16_t sA[128 * 64];
    __shared__ __align__(16) bf16_t sB[128 * 64];

    int tid = threadIdx.x;
    int lane = tid & 63, wave = tid >> 6;
    int wm = wave & 1, wn = wave >> 1;
    int quad = lane >> 4, l16 = lane & 15;

    f32x4 acc[4][4];
    f32x4 z = {0.f, 0.f, 0.f, 0.f};
#pragma unroll
    for (int i = 0; i < 4; ++i)
#pragma unroll
        for (int j = 0; j < 4; ++j) acc[i][j] = z;

    for (int kt = 0; kt < K / 64; ++kt) {
        __syncthreads();
        stage_tile(A + kt * 64, K, sA, tid);
        stage_tile(B + kt * 64, K, sB, tid);
        __syncthreads();
#pragma unroll
        for (int kk = 0; kk < 2; ++kk) {
            int chunk = kk * 4 + quad;
            bf16x8 af[4], bf[4];
#pragma unroll
            for (int i = 0; i < 4; ++i) af[i] = read_frag(sA, wm * 64 + i * 16 + l16, chunk);
#pragma unroll
            for (int j = 0; j < 4; ++j) bf[j] = read_frag(sB, wn * 64 + j * 16 + l16, chunk);
#pragma unroll
            for (int i = 0; i < 4; ++i)
#pragma unroll
                for (int j = 0; j < 4; ++j)
                    acc[i][j] = MFMA16(af[i], bf[j], acc[i][j]);
        }
    }

#pragma unroll
    for (int i = 0; i < 4; ++i)
#pragma unroll
        for (int j = 0; j < 4; ++j) {
            int r = row0 + wm * 64 + i * 16 + quad * 4;
            int c = col0 + wn * 64 + j * 16 + l16;
#pragma unroll
            for (int t = 0; t < 4; ++t)
                Outc[(size_t)(r + t) * N + c] = acc[i][j][t];
        }
}

extern "C" void kernel_launch(void* const* d_in, const int* in_sizes, int n_in,
                              void* d_out, int out_size, void* d_ws, size_t ws_size,
                              hipStream_t stream) {
    const float* x  = (const float*)d_in[0];   // fp32 [8,2048,1024]
    const float* w1 = (const float*)d_in[1];   // fp32 [4,1024,2048]
    const float* w3 = (const float*)d_in[2];   // fp32 [4,1024,2048]
    const float* w2 = (const float*)d_in[3];   // fp32 [4,2048,1024]
    float* out = (float*)d_out;                // fp32 [8,2048,1024]

    const size_t WSEG = (size_t)4 * 1024 * 2048; // elems per weight tensor
    bf16_t* w1t = (bf16_t*)d_ws;                 // bf16 [4][2048][1024]
    bf16_t* w3t = w1t + WSEG;                    // bf16 [4][2048][1024]
    bf16_t* w2t = w3t + WSEG;                    // bf16 [4][1024][2048]
    bf16_t* dyn = w2t + WSEG;                    // Xb chunk + Hh chunk

    transcvt64<<<dim3(32, 16, 4), 256, 0, stream>>>(w1, (unsigned short*)w1t, 1024, 2048);
    transcvt64<<<dim3(32, 16, 4), 256, 0, stream>>>(w3, (unsigned short*)w3t, 1024, 2048);
    transcvt64<<<dim3(16, 32, 4), 256, 0, stream>>>(w2, (unsigned short*)w2t, 2048, 1024);

    // Adaptive chunking: per-chunk ws = Xb (R*1024*2 B) + Hh (R*2048*2 B).
    // ws_size is a host constant per run -> identical work every call.
    const int TOTAL_ROWS = 16384;
    size_t wbytes = 3 * WSEG * sizeof(bf16_t);   // 50.3 MB weights
    size_t avail = (ws_size > wbytes) ? ws_size - wbytes : 0;
    int chunk_rows = TOTAL_ROWS;
    while (chunk_rows > 128 && (size_t)chunk_rows * 6144 > avail)
        chunk_rows >>= 1;

    for (int rb = 0; rb < TOTAL_ROWS; rb += chunk_rows) {
        bf16_t* Xb = dyn;                                   // [R,1024] bf16
        bf16_t* Hh = dyn + (size_t)chunk_rows * 1024;       // [R,2048] bf16
        cvtx<<<chunk_rows / 2, 256, 0, stream>>>(x + (size_t)rb * 1024, Xb);
        gemm13<<<dim3(16, chunk_rows / 128), 256, 0, stream>>>(
            Xb, w1t, w3t, Hh, rb);
        gemm2k<<<dim3(8, chunk_rows / 128), 256, 0, stream>>>(
            Hh, w2t, out + (size_t)rb * 1024, rb);
    }
}

// Round 6
// 555.802 us; speedup vs baseline: 1.1093x; 1.0347x over previous
//
#include <hip/hip_runtime.h>
#include <hip/hip_bf16.h>

typedef __bf16 bf16_t;
typedef __attribute__((ext_vector_type(8))) __bf16 bf16x8;
typedef __attribute__((ext_vector_type(4))) float f32x4;

#define MFMA16(a, b, c) __builtin_amdgcn_mfma_f32_16x16x32_bf16((a), (b), (c), 0, 0, 0)

__device__ __forceinline__ unsigned short f2bf(float f) {
    bf16_t b = (bf16_t)f;
    return __builtin_bit_cast(unsigned short, b);
}

__device__ __forceinline__ void gload16(const void* g, void* l) {
    __builtin_amdgcn_global_load_lds(
        (const __attribute__((address_space(1))) void*)g,
        (__attribute__((address_space(3))) void*)l,
        16, 0, 0);
}

// Stage a 128(rows) x 64(k) bf16 tile from global (row-major, ld elems) into
// LDS via global_load_lds. XOR chunk-of-8 swizzle: LDS slot s of row r holds
// global k-chunk (s ^ (r&7)) — permutation is applied on the GLOBAL side
// (legal gather: same 128B line), LDS side stays wave-uniform base + lane*16
// as the HW requires. Kills the 16-way bank conflict on fragment reads.
__device__ __forceinline__ void stage_tile(const bf16_t* __restrict__ g, int ld,
                                           bf16_t* lds, int tid) {
#pragma unroll
    for (int p = 0; p < 4; ++p) {
        int row = p * 32 + (tid >> 3);
        int c = (tid & 7) ^ (row & 7);   // global chunk for this LDS slot
        gload16(g + (size_t)row * ld + c * 8, lds + p * 2048 + tid * 8);
    }
}

// Read one 8-bf16 fragment (row r, k-chunk 'chunk') from a swizzled tile.
// Quad's 16 lanes read rows r..r+15 -> slots span all 8 values -> banks
// spread across all 32, 2-way aliasing only (free per m136).
__device__ __forceinline__ bf16x8 read_frag(const bf16_t* lds, int r, int chunk) {
    int s = chunk ^ (r & 7);
    return *(const bf16x8*)(lds + r * 64 + s * 8);
}

// ---------- fp32 -> bf16 elementwise convert (for X) ----------
__global__ __launch_bounds__(256) void cvtx(const float* __restrict__ src,
                                            bf16_t* __restrict__ dst) {
    size_t i = ((size_t)blockIdx.x * 256 + threadIdx.x) * 8;
    f32x4 v0 = *(const f32x4*)(src + i);
    f32x4 v1 = *(const f32x4*)(src + i + 4);
    bf16x8 o;
    o[0] = (bf16_t)v0[0]; o[1] = (bf16_t)v0[1];
    o[2] = (bf16_t)v0[2]; o[3] = (bf16_t)v0[3];
    o[4] = (bf16_t)v1[0]; o[5] = (bf16_t)v1[1];
    o[6] = (bf16_t)v1[2]; o[7] = (bf16_t)v1[3];
    *(bf16x8*)(dst + i) = o;
}

// ---------- batched 64x64 transpose + fp32->bf16 convert ----------
__global__ __launch_bounds__(256) void transcvt64(const float* __restrict__ src,
                                                  unsigned short* __restrict__ dst,
                                                  int R, int C) {
    __shared__ __align__(16) unsigned short tile[64][66];
    size_t off = (size_t)blockIdx.z * R * C;
    const float* s = src + off;
    unsigned short* d = dst + off;
    int tr = blockIdx.y * 64, tc = blockIdx.x * 64;
    int tid = threadIdx.x;
    int lr = tid >> 4;
    int lc = (tid & 15) * 4;
#pragma unroll
    for (int p = 0; p < 4; ++p) {
        int r = p * 16 + lr;
        f32x4 v = *(const f32x4*)(s + (size_t)(tr + r) * C + tc + lc);
        tile[r][lc + 0] = f2bf(v[0]); tile[r][lc + 1] = f2bf(v[1]);
        tile[r][lc + 2] = f2bf(v[2]); tile[r][lc + 3] = f2bf(v[3]);
    }
    __syncthreads();
#pragma unroll
    for (int p = 0; p < 4; ++p) {
        int oc = p * 16 + lr;
        ushort4 v;
        v.x = tile[lc + 0][oc]; v.y = tile[lc + 1][oc];
        v.z = tile[lc + 2][oc]; v.w = tile[lc + 3][oc];
        *(ushort4*)(d + (size_t)(tc + oc) * R + tr + lc) = v;
    }
}

// ---------- GEMM1: U = X*W1, V = X*W3, Hh = silu(U)*V ----------
// Grid: (R/128 row-tiles, 16 col-tiles) — row fastest: all 16 col-blocks of a
// row-strip land on XCD row%8 (A fetched once); weight tiles stream via L2/L3.
__global__ __launch_bounds__(256, 3) void gemm13(const bf16_t* __restrict__ Xb,
                                                 const bf16_t* __restrict__ W1t,
                                                 const bf16_t* __restrict__ W3t,
                                                 bf16_t* __restrict__ Hh,
                                                 int row_base) {
    const int K = 1024, N = 2048;
    int row0 = blockIdx.x * 128;
    int col0 = blockIdx.y * 128;
    int seg = ((row_base + row0) & 2047) >> 9;
    const bf16_t* A  = Xb + (size_t)row0 * K;
    const bf16_t* B1 = W1t + (size_t)seg * N * K + (size_t)col0 * K;
    const bf16_t* B3 = W3t + (size_t)seg * N * K + (size_t)col0 * K;

    __shared__ __align__(16) bf16_t sA[128 * 64];
    __shared__ __align__(16) bf16_t sB1[128 * 64];
    __shared__ __align__(16) bf16_t sB3[128 * 64];

    int tid = threadIdx.x;
    int lane = tid & 63, wave = tid >> 6;
    int wm = wave & 1, wn = wave >> 1;
    int quad = lane >> 4, l16 = lane & 15;

    f32x4 accU[4][4], accV[4][4];
    f32x4 z = {0.f, 0.f, 0.f, 0.f};
#pragma unroll
    for (int i = 0; i < 4; ++i)
#pragma unroll
        for (int j = 0; j < 4; ++j) { accU[i][j] = z; accV[i][j] = z; }

    for (int kt = 0; kt < K / 64; ++kt) {
        __syncthreads();
        stage_tile(A + kt * 64, K, sA, tid);
        stage_tile(B1 + kt * 64, K, sB1, tid);
        stage_tile(B3 + kt * 64, K, sB3, tid);
        __syncthreads();
#pragma unroll
        for (int kk = 0; kk < 2; ++kk) {
            int chunk = kk * 4 + quad;
            bf16x8 af[4], b1f[4], b3f[4];
#pragma unroll
            for (int i = 0; i < 4; ++i) af[i] = read_frag(sA, wm * 64 + i * 16 + l16, chunk);
#pragma unroll
            for (int j = 0; j < 4; ++j) b1f[j] = read_frag(sB1, wn * 64 + j * 16 + l16, chunk);
#pragma unroll
            for (int j = 0; j < 4; ++j) b3f[j] = read_frag(sB3, wn * 64 + j * 16 + l16, chunk);
#pragma unroll
            for (int i = 0; i < 4; ++i)
#pragma unroll
                for (int j = 0; j < 4; ++j) {
                    accU[i][j] = MFMA16(af[i], b1f[j], accU[i][j]);
                    accV[i][j] = MFMA16(af[i], b3f[j], accV[i][j]);
                }
        }
    }

#pragma unroll
    for (int i = 0; i < 4; ++i)
#pragma unroll
        for (int j = 0; j < 4; ++j) {
            int r = row0 + wm * 64 + i * 16 + quad * 4;
            int c = col0 + wn * 64 + j * 16 + l16;
#pragma unroll
            for (int t = 0; t < 4; ++t) {
                float u = accU[i][j][t];
                float v = accV[i][j][t];
                float h = (u / (1.f + __expf(-u))) * v;
                Hh[(size_t)(r + t) * N + c] = (bf16_t)h;
            }
        }
}

// ---------- GEMM2: Out = Hh * W2 ----------
// Grid: (R/128 row-tiles, 8 col-tiles) — row fastest (Hh is the big tensor).
__global__ __launch_bounds__(256, 3) void gemm2k(const bf16_t* __restrict__ Hh,
                                                 const bf16_t* __restrict__ W2t,
                                                 float* __restrict__ Outc,
                                                 int row_base) {
    const int K = 2048, N = 1024;
    int row0 = blockIdx.x * 128;
    int col0 = blockIdx.y * 128;
    int seg = ((row_base + row0) & 2047) >> 9;
    const bf16_t* A = Hh + (size_t)row0 * K;
    const bf16_t* B = W2t + (size_t)seg * N * K + (size_t)col0 * K;

    __shared__ __align__(16) bf16_t sA[128 * 64];
    __shared__ __align__(16) bf16_t sB[128 * 64];

    int tid = threadIdx.x;
    int lane = tid & 63, wave = tid >> 6;
    int wm = wave & 1, wn = wave >> 1;
    int quad = lane >> 4, l16 = lane & 15;

    f32x4 acc[4][4];
    f32x4 z = {0.f, 0.f, 0.f, 0.f};
#pragma unroll
    for (int i = 0; i < 4; ++i)
#pragma unroll
        for (int j = 0; j < 4; ++j) acc[i][j] = z;

    for (int kt = 0; kt < K / 64; ++kt) {
        __syncthreads();
        stage_tile(A + kt * 64, K, sA, tid);
        stage_tile(B + kt * 64, K, sB, tid);
        __syncthreads();
#pragma unroll
        for (int kk = 0; kk < 2; ++kk) {
            int chunk = kk * 4 + quad;
            bf16x8 af[4], bf[4];
#pragma unroll
            for (int i = 0; i < 4; ++i) af[i] = read_frag(sA, wm * 64 + i * 16 + l16, chunk);
#pragma unroll
            for (int j = 0; j < 4; ++j) bf[j] = read_frag(sB, wn * 64 + j * 16 + l16, chunk);
#pragma unroll
            for (int i = 0; i < 4; ++i)
#pragma unroll
                for (int j = 0; j < 4; ++j)
                    acc[i][j] = MFMA16(af[i], bf[j], acc[i][j]);
        }
    }

#pragma unroll
    for (int i = 0; i < 4; ++i)
#pragma unroll
        for (int j = 0; j < 4; ++j) {
            int r = row0 + wm * 64 + i * 16 + quad * 4;
            int c = col0 + wn * 64 + j * 16 + l16;
#pragma unroll
            for (int t = 0; t < 4; ++t)
                Outc[(size_t)(r + t) * N + c] = acc[i][j][t];
        }
}

extern "C" void kernel_launch(void* const* d_in, const int* in_sizes, int n_in,
                              void* d_out, int out_size, void* d_ws, size_t ws_size,
                              hipStream_t stream) {
    const float* x  = (const float*)d_in[0];   // fp32 [8,2048,1024]
    const float* w1 = (const float*)d_in[1];   // fp32 [4,1024,2048]
    const float* w3 = (const float*)d_in[2];   // fp32 [4,1024,2048]
    const float* w2 = (const float*)d_in[3];   // fp32 [4,2048,1024]
    float* out = (float*)d_out;                // fp32 [8,2048,1024]

    const size_t WSEG = (size_t)4 * 1024 * 2048;
    bf16_t* w1t = (bf16_t*)d_ws;                 // bf16 [4][2048][1024]
    bf16_t* w3t = w1t + WSEG;
    bf16_t* w2t = w3t + WSEG;                    // bf16 [4][1024][2048]
    bf16_t* dyn = w2t + WSEG;                    // Xb chunk + Hh chunk

    transcvt64<<<dim3(32, 16, 4), 256, 0, stream>>>(w1, (unsigned short*)w1t, 1024, 2048);
    transcvt64<<<dim3(32, 16, 4), 256, 0, stream>>>(w3, (unsigned short*)w3t, 1024, 2048);
    transcvt64<<<dim3(16, 32, 4), 256, 0, stream>>>(w2, (unsigned short*)w2t, 2048, 1024);

    const int TOTAL_ROWS = 16384;
    size_t wbytes = 3 * WSEG * sizeof(bf16_t);
    size_t avail = (ws_size > wbytes) ? ws_size - wbytes : 0;
    int chunk_rows = TOTAL_ROWS;
    while (chunk_rows > 128 && (size_t)chunk_rows * 6144 > avail)
        chunk_rows >>= 1;

    for (int rb = 0; rb < TOTAL_ROWS; rb += chunk_rows) {
        bf16_t* Xb = dyn;
        bf16_t* Hh = dyn + (size_t)chunk_rows * 1024;
        cvtx<<<chunk_rows / 2, 256, 0, stream>>>(x + (size_t)rb * 1024, Xb);
        gemm13<<<dim3(chunk_rows / 128, 16), 256, 0, stream>>>(
            Xb, w1t, w3t, Hh, rb);
        gemm2k<<<dim3(chunk_rows / 128, 8), 256, 0, stream>>>(
            Hh, w2t, out + (size_t)rb * 1024, rb);
    }
}

// Round 7
// 422.491 us; speedup vs baseline: 1.4593x; 1.3155x over previous
//
#include <hip/hip_runtime.h>
#include <hip/hip_bf16.h>

typedef __bf16 bf16_t;
typedef __attribute__((ext_vector_type(8))) __bf16 bf16x8;
typedef __attribute__((ext_vector_type(4))) float f32x4;

#define MFMA16(a, b, c) __builtin_amdgcn_mfma_f32_16x16x32_bf16((a), (b), (c), 0, 0, 0)

__device__ __forceinline__ unsigned short f2bf(float f) {
    bf16_t b = (bf16_t)f;
    return __builtin_bit_cast(unsigned short, b);
}

__device__ __forceinline__ void gload16(const void* g, void* l) {
    __builtin_amdgcn_global_load_lds(
        (const __attribute__((address_space(1))) void*)g,
        (__attribute__((address_space(3))) void*)l,
        16, 0, 0);
}

// Stage a 128x64 bf16 tile global->LDS via global_load_lds with XOR chunk
// swizzle on the global side (slot s of row r holds chunk s^(r&7)); LDS side
// stays wave-uniform base + lane*16 as HW requires. Conflict-free frag reads.
__device__ __forceinline__ void stage_tile(const bf16_t* __restrict__ g, int ld,
                                           bf16_t* lds, int tid) {
#pragma unroll
    for (int p = 0; p < 4; ++p) {
        int row = p * 32 + (tid >> 3);
        int c = (tid & 7) ^ (row & 7);
        gload16(g + (size_t)row * ld + c * 8, lds + p * 2048 + tid * 8);
    }
}

__device__ __forceinline__ bf16x8 read_frag(const bf16_t* lds, int r, int chunk) {
    int s = chunk ^ (r & 7);
    return *(const bf16x8*)(lds + r * 64 + s * 8);
}

// ---------- fp32 -> bf16 elementwise convert (for X) ----------
__global__ __launch_bounds__(256) void cvtx(const float* __restrict__ src,
                                            bf16_t* __restrict__ dst) {
    size_t i = ((size_t)blockIdx.x * 256 + threadIdx.x) * 8;
    f32x4 v0 = *(const f32x4*)(src + i);
    f32x4 v1 = *(const f32x4*)(src + i + 4);
    bf16x8 o;
    o[0] = (bf16_t)v0[0]; o[1] = (bf16_t)v0[1];
    o[2] = (bf16_t)v0[2]; o[3] = (bf16_t)v0[3];
    o[4] = (bf16_t)v1[0]; o[5] = (bf16_t)v1[1];
    o[6] = (bf16_t)v1[2]; o[7] = (bf16_t)v1[3];
    *(bf16x8*)(dst + i) = o;
}

// ---------- batched 64x64 transpose + fp32->bf16 convert ----------
__global__ __launch_bounds__(256) void transcvt64(const float* __restrict__ src,
                                                  unsigned short* __restrict__ dst,
                                                  int R, int C) {
    __shared__ __align__(16) unsigned short tile[64][66];
    size_t off = (size_t)blockIdx.z * R * C;
    const float* s = src + off;
    unsigned short* d = dst + off;
    int tr = blockIdx.y * 64, tc = blockIdx.x * 64;
    int tid = threadIdx.x;
    int lr = tid >> 4;
    int lc = (tid & 15) * 4;
#pragma unroll
    for (int p = 0; p < 4; ++p) {
        int r = p * 16 + lr;
        f32x4 v = *(const f32x4*)(s + (size_t)(tr + r) * C + tc + lc);
        tile[r][lc + 0] = f2bf(v[0]); tile[r][lc + 1] = f2bf(v[1]);
        tile[r][lc + 2] = f2bf(v[2]); tile[r][lc + 3] = f2bf(v[3]);
    }
    __syncthreads();
#pragma unroll
    for (int p = 0; p < 4; ++p) {
        int oc = p * 16 + lr;
        ushort4 v;
        v.x = tile[lc + 0][oc]; v.y = tile[lc + 1][oc];
        v.z = tile[lc + 2][oc]; v.w = tile[lc + 3][oc];
        *(ushort4*)(d + (size_t)(tc + oc) * R + tr + lc) = v;
    }
}

// ---------- GEMM1: U = X*W1, V = X*W3, Hh = silu(U)*V ----------
__global__ __launch_bounds__(256, 3) void gemm13(const bf16_t* __restrict__ Xb,
                                                 const bf16_t* __restrict__ W1t,
                                                 const bf16_t* __restrict__ W3t,
                                                 bf16_t* __restrict__ Hh,
                                                 int row_base) {
    const int K = 1024, N = 2048;
    int row0 = blockIdx.x * 128;
    int col0 = blockIdx.y * 128;
    int seg = ((row_base + row0) & 2047) >> 9;
    const bf16_t* A  = Xb + (size_t)row0 * K;
    const bf16_t* B1 = W1t + (size_t)seg * N * K + (size_t)col0 * K;
    const bf16_t* B3 = W3t + (size_t)seg * N * K + (size_t)col0 * K;

    // one 48 KB pool: staging (3 x 16 KB) during K-loop; C-repack (34.8 KB) after
    __shared__ __align__(16) bf16_t smem[3 * 128 * 64];
    bf16_t* sA  = smem;
    bf16_t* sB1 = smem + 8192;
    bf16_t* sB3 = smem + 16384;

    int tid = threadIdx.x;
    int lane = tid & 63, wave = tid >> 6;
    int wm = wave & 1, wn = wave >> 1;
    int quad = lane >> 4, l16 = lane & 15;

    f32x4 accU[4][4], accV[4][4];
    f32x4 z = {0.f, 0.f, 0.f, 0.f};
#pragma unroll
    for (int i = 0; i < 4; ++i)
#pragma unroll
        for (int j = 0; j < 4; ++j) { accU[i][j] = z; accV[i][j] = z; }

    for (int kt = 0; kt < K / 64; ++kt) {
        __syncthreads();
        stage_tile(A + kt * 64, K, sA, tid);
        stage_tile(B1 + kt * 64, K, sB1, tid);
        stage_tile(B3 + kt * 64, K, sB3, tid);
        __syncthreads();
#pragma unroll
        for (int kk = 0; kk < 2; ++kk) {
            int chunk = kk * 4 + quad;
            bf16x8 af[4], b1f[4], b3f[4];
#pragma unroll
            for (int i = 0; i < 4; ++i) af[i] = read_frag(sA, wm * 64 + i * 16 + l16, chunk);
#pragma unroll
            for (int j = 0; j < 4; ++j) b1f[j] = read_frag(sB1, wn * 64 + j * 16 + l16, chunk);
#pragma unroll
            for (int j = 0; j < 4; ++j) b3f[j] = read_frag(sB3, wn * 64 + j * 16 + l16, chunk);
#pragma unroll
            for (int i = 0; i < 4; ++i)
#pragma unroll
                for (int j = 0; j < 4; ++j) {
                    accU[i][j] = MFMA16(af[i], b1f[j], accU[i][j]);
                    accV[i][j] = MFMA16(af[i], b3f[j], accV[i][j]);
                }
        }
    }

    // Epilogue: silu(U)*V -> LDS (bf16, stride 136) -> full-line stores.
    __syncthreads();                      // all frag reads done; reuse smem
    bf16_t* Ct = smem;                    // 128 x 136, max idx 17407 < 24576
#pragma unroll
    for (int i = 0; i < 4; ++i)
#pragma unroll
        for (int j = 0; j < 4; ++j) {
            int r = wm * 64 + i * 16 + quad * 4;
            int c = wn * 64 + j * 16 + l16;
#pragma unroll
            for (int t = 0; t < 4; ++t) {
                float u = accU[i][j][t];
                float v = accV[i][j][t];
                float h = (u / (1.f + __expf(-u))) * v;
                Ct[(r + t) * 136 + c] = (bf16_t)h;
            }
        }
    __syncthreads();
    // 16 lanes cover one row's full 256 B (2 whole lines) per instruction.
#pragma unroll
    for (int s = 0; s < 8; ++s) {
        int r = s * 16 + wave * 4 + (lane >> 4);
        int cb = (lane & 15) * 8;
        bf16x8 v = *(const bf16x8*)(Ct + r * 136 + cb);
        *(bf16x8*)(Hh + (size_t)(row0 + r) * N + col0 + cb) = v;
    }
}

// ---------- GEMM2: Out = Hh * W2 ----------
__global__ __launch_bounds__(256, 3) void gemm2k(const bf16_t* __restrict__ Hh,
                                                 const bf16_t* __restrict__ W2t,
                                                 float* __restrict__ Outc,
                                                 int row_base) {
    const int K = 2048, N = 1024;
    int row0 = blockIdx.x * 128;
    int col0 = blockIdx.y * 128;
    int seg = ((row_base + row0) & 2047) >> 9;
    const bf16_t* A = Hh + (size_t)row0 * K;
    const bf16_t* B = W2t + (size_t)seg * N * K + (size_t)col0 * K;

    // pool: staging 32 KB (2 x 16 KB bf16) during K-loop; f32 repack 64x130 after
    __shared__ __align__(16) float smemf[64 * 130];     // 33.3 KB
    bf16_t* sA = (bf16_t*)smemf;
    bf16_t* sB = sA + 8192;

    int tid = threadIdx.x;
    int lane = tid & 63, wave = tid >> 6;
    int wm = wave & 1, wn = wave >> 1;
    int quad = lane >> 4, l16 = lane & 15;

    f32x4 acc[4][4];
    f32x4 z = {0.f, 0.f, 0.f, 0.f};
#pragma unroll
    for (int i = 0; i < 4; ++i)
#pragma unroll
        for (int j = 0; j < 4; ++j) acc[i][j] = z;

    for (int kt = 0; kt < K / 64; ++kt) {
        __syncthreads();
        stage_tile(A + kt * 64, K, sA, tid);
        stage_tile(B + kt * 64, K, sB, tid);
        __syncthreads();
#pragma unroll
        for (int kk = 0; kk < 2; ++kk) {
            int chunk = kk * 4 + quad;
            bf16x8 af[4], bf[4];
#pragma unroll
            for (int i = 0; i < 4; ++i) af[i] = read_frag(sA, wm * 64 + i * 16 + l16, chunk);
#pragma unroll
            for (int j = 0; j < 4; ++j) bf[j] = read_frag(sB, wn * 64 + j * 16 + l16, chunk);
#pragma unroll
            for (int i = 0; i < 4; ++i)
#pragma unroll
                for (int j = 0; j < 4; ++j)
                    acc[i][j] = MFMA16(af[i], bf[j], acc[i][j]);
        }
    }

    // Epilogue: two 64-row passes through f32 LDS, full-line (512 B/row) stores.
    for (int pass = 0; pass < 2; ++pass) {
        __syncthreads();
        if (wm == pass) {
#pragma unroll
            for (int i = 0; i < 4; ++i)
#pragma unroll
                for (int j = 0; j < 4; ++j) {
                    int r = i * 16 + quad * 4;          // local row 0..63
                    int c = wn * 64 + j * 16 + l16;
#pragma unroll
                    for (int t = 0; t < 4; ++t)
                        smemf[(r + t) * 130 + c] = acc[i][j][t];
                }
        }
        __syncthreads();
        // 32 lanes cover one row's full 512 B (4 whole lines) per instruction.
#pragma unroll
        for (int s = 0; s < 8; ++s) {
            int r = s * 8 + wave * 2 + (lane >> 5);
            int cb = (lane & 31) * 4;
            f32x4 v = *(const f32x4*)(smemf + r * 130 + cb);
            *(f32x4*)(Outc + (size_t)(row0 + pass * 64 + r) * N + col0 + cb) = v;
        }
    }
}

extern "C" void kernel_launch(void* const* d_in, const int* in_sizes, int n_in,
                              void* d_out, int out_size, void* d_ws, size_t ws_size,
                              hipStream_t stream) {
    const float* x  = (const float*)d_in[0];   // fp32 [8,2048,1024]
    const float* w1 = (const float*)d_in[1];   // fp32 [4,1024,2048]
    const float* w3 = (const float*)d_in[2];   // fp32 [4,1024,2048]
    const float* w2 = (const float*)d_in[3];   // fp32 [4,2048,1024]
    float* out = (float*)d_out;                // fp32 [8,2048,1024]

    const size_t WSEG = (size_t)4 * 1024 * 2048;
    bf16_t* w1t = (bf16_t*)d_ws;
    bf16_t* w3t = w1t + WSEG;
    bf16_t* w2t = w3t + WSEG;
    bf16_t* dyn = w2t + WSEG;

    transcvt64<<<dim3(32, 16, 4), 256, 0, stream>>>(w1, (unsigned short*)w1t, 1024, 2048);
    transcvt64<<<dim3(32, 16, 4), 256, 0, stream>>>(w3, (unsigned short*)w3t, 1024, 2048);
    transcvt64<<<dim3(16, 32, 4), 256, 0, stream>>>(w2, (unsigned short*)w2t, 2048, 1024);

    const int TOTAL_ROWS = 16384;
    size_t wbytes = 3 * WSEG * sizeof(bf16_t);
    size_t avail = (ws_size > wbytes) ? ws_size - wbytes : 0;
    int chunk_rows = TOTAL_ROWS;
    while (chunk_rows > 128 && (size_t)chunk_rows * 6144 > avail)
        chunk_rows >>= 1;

    for (int rb = 0; rb < TOTAL_ROWS; rb += chunk_rows) {
        bf16_t* Xb = dyn;
        bf16_t* Hh = dyn + (size_t)chunk_rows * 1024;
        cvtx<<<chunk_rows / 2, 256, 0, stream>>>(x + (size_t)rb * 1024, Xb);
        gemm13<<<dim3(chunk_rows / 128, 16), 256, 0, stream>>>(
            Xb, w1t, w3t, Hh, rb);
        gemm2k<<<dim3(chunk_rows / 128, 8), 256, 0, stream>>>(
            Hh, w2t, out + (size_t)rb * 1024, rb);
    }
}